// Round 5
// baseline (255.387 us; speedup 1.0000x reference)
//
#include <hip/hip_runtime.h>
#include <math.h>

// DivMergedLayer1: reference collapses to out = x except 4 floats per row.
//   N=32, D=128, F=4096, B=8192. Flat row layout: x[b, n, d] -> xr[n*128 + d].
//   op  = xr[67]            (OP_START+OPCODE = 64+3, nibble row 0)
//   r60 = relu(60*op); inv60 = fp32(1/60)
//   P   = sum_{i=0..31} 2^i * xr[i*128 + 0]     (gate reads NIB_A = col 0)
//   float64 path over d_i = (double)xr[i*128 + 1]   (NIB_B = col 1):
//     score_i = d_i > 0.5 ? log(max(d_i*2^i, 0.5)) : -60
//     recip = exp(-mx)/max(sum exp(score-mx), 1e-30)
//   out[2] = x2 - r60*x2/60 + r60*P/60
//   out[3,4] = x - r60*x/60
//   out[5] = x5 - r60*x5/60 + op*(float)recip
//   out elsewhere = x exactly.
//
// R2/R3: row-per-block copy + fused fix = 2.5 TB/s (latency/structure bound;
// fillBuffer hits 6.3 TB/s in same capture). R4 A/B: (A) textbook grid-stride
// vec4 copy w/ 4-deep MLP and non-temporal stores; (B) separate tiny fix
// kernel that overwrites 16 B per row, stream-ordered after A.
// R4 compile fix: __builtin_nontemporal_store needs a NATIVE vector type,
// not HIP_vector_type float4 -> use ext_vector_type(4) float.

#define DDIM 128
#define FDIM 4096

typedef float vfloat4 __attribute__((ext_vector_type(4)));

__global__ __launch_bounds__(256) void copy_kernel(
    const vfloat4* __restrict__ x4, vfloat4* __restrict__ o4, long long n4) {
  const long long stride = (long long)gridDim.x * blockDim.x;
  long long i = (long long)blockIdx.x * blockDim.x + threadIdx.x;
  // 4 independent loads in flight per iteration.
  for (; i + 3 * stride < n4; i += 4 * stride) {
    vfloat4 a = x4[i];
    vfloat4 b = x4[i + stride];
    vfloat4 c = x4[i + 2 * stride];
    vfloat4 d = x4[i + 3 * stride];
    __builtin_nontemporal_store(a, o4 + i);
    __builtin_nontemporal_store(b, o4 + i + stride);
    __builtin_nontemporal_store(c, o4 + i + 2 * stride);
    __builtin_nontemporal_store(d, o4 + i + 3 * stride);
  }
  for (; i < n4; i += stride) {
    vfloat4 a = x4[i];
    __builtin_nontemporal_store(a, o4 + i);
  }
}

// One 32-lane half-wave per row; 2 rows per wave; 8 rows per 256-thread block.
__global__ __launch_bounds__(256) void fix_kernel(
    const float* __restrict__ x, float* __restrict__ out, int rows) {
  const int t = threadIdx.x;
  const int wave = t >> 6;
  const int lane = t & 63;
  const int half = lane >> 5;
  const int sl = lane & 31;
  const long long row = (long long)blockIdx.x * 8 + wave * 2 + half;
  if (row >= rows) return;
  const float* __restrict__ xr = x + row * (long long)FDIM;
  float* __restrict__ orow = out + row * (long long)FDIM;

  const float2 ab = *(const float2*)(xr + sl * DDIM);  // cols 0,1 of nibble sl
  const double pw = (double)(1U << sl);                // 2^sl, exact
  double p = (double)ab.x * pw;
  const double d = (double)ab.y;
  double score = (d > 0.5) ? log(fmax(d * pw, 0.5)) : -60.0;

  // width-32 butterflies (xor of bits 0..4 stays within the 32-half)
  double mx = score;
#pragma unroll
  for (int off = 1; off < 32; off <<= 1)
    mx = fmax(mx, __shfl_xor(mx, off));
  double ex = exp(score - mx);
#pragma unroll
  for (int off = 1; off < 32; off <<= 1) {
    ex += __shfl_xor(ex, off);
    p  += __shfl_xor(p, off);
  }
  if (sl == 0) {
    const float op    = xr[64 + 3];  // flat 67
    const float r60   = fmaxf(60.0f * op, 0.0f);
    const float inv60 = (float)(1.0 / 60.0);
    const double recip = exp(-mx) / fmax(ex, 1e-30);
    const float Pf = (float)p;
    const float x2 = xr[2], x3 = xr[3], x4v = xr[4], x5 = xr[5];
    float2 f23, f45;
    f23.x = x2 + (-((r60 * x2) * inv60) + (r60 * Pf) * inv60);
    f23.y = x3 - (r60 * x3) * inv60;
    f45.x = x4v - (r60 * x4v) * inv60;
    f45.y = (x5 - (r60 * x5) * inv60) + op * (float)recip;
    *(float2*)(orow + 2) = f23;  // flats 2,3
    *(float2*)(orow + 4) = f45;  // flats 4,5
  }
}

extern "C" void kernel_launch(void* const* d_in, const int* in_sizes, int n_in,
                              void* d_out, int out_size, void* d_ws, size_t ws_size,
                              hipStream_t stream) {
  const float* x = (const float*)d_in[0];  // (B, 32, 128) fp32
  float* out = (float*)d_out;              // (B, 32, 128) fp32
  const int rows = in_sizes[0] / FDIM;     // B = 8192
  const long long n4 = (long long)rows * (FDIM / 4);

  copy_kernel<<<2048, 256, 0, stream>>>((const vfloat4*)x, (vfloat4*)out, n4);
  fix_kernel<<<(rows + 7) / 8, 256, 0, stream>>>(x, out, rows);
}